// Round 2
// baseline (13494.696 us; speedup 1.0000x reference)
//
#include <hip/hip_runtime.h>
#include <hip/hip_bf16.h>
#include <stddef.h>

// Problem constants
#define BB 128     // batch
#define LL 64      // feature pixels
#define TT 20      // decode steps
#define VV 32000   // vocab
#define EE 512     // embed
#define HH 1024    // hidden
#define AA 512     // attn dim
#define FF 2048    // num_features

// ---------------------------------------------------------------------------
// mean over L axis: mean_ann[b,f] = (1/L) sum_l X[b,l,f]
__global__ __launch_bounds__(256) void mean_kernel(const float* __restrict__ X,
                                                   float* __restrict__ mean_ann) {
    int idx = blockIdx.x * 256 + threadIdx.x;    // over B*F
    int b = idx >> 11, f = idx & (FF - 1);
    const float* p = X + (size_t)b * LL * FF + f;
    float s = 0.f;
    #pragma unroll
    for (int l = 0; l < LL; ++l) s += p[l * FF];
    mean_ann[idx] = s * (1.0f / LL);
}

// ---------------------------------------------------------------------------
// Tiled GEMM: C[M,N] = A[M,K] @ W[K,N] (+bias [+bias2])
// MODE 0: A fp32 contiguous; MODE 2: A = [emb(y[:,t]) | context | h], W = [w_ih ; w_hh]
// 256 threads; BK=32; thread tile TM x TN.
template<int BM, int BN, int TM, int TN, int MODE>
__global__ __launch_bounds__(256)
void tgemm(const float* __restrict__ Aptr,
           const float* __restrict__ ctx, const float* __restrict__ hptr,
           const float* __restrict__ emb, const int* __restrict__ y, int t,
           const float* __restrict__ W, const float* __restrict__ W2,
           const float* __restrict__ bias, const float* __restrict__ bias2,
           float* __restrict__ C, int N, int K, int Cstride)
{
    constexpr int BK = 32;
    constexpr int PAD = 4;
    __shared__ float lds_a[BK][BM + PAD];
    __shared__ float lds_w[BK][BN + PAD];
    const int tid = threadIdx.x;
    const int nblk = blockIdx.x * BN;
    const int mblk = blockIdx.y * BM;
    constexpr int NG = BN / TN;                 // n-groups
    const int tn = (tid % NG) * TN;
    const int tm = (tid / NG) * TM;

    float acc[TM][TN];
    #pragma unroll
    for (int i = 0; i < TM; ++i)
        #pragma unroll
        for (int j = 0; j < TN; ++j) acc[i][j] = 0.f;

    constexpr int A_ELEMS = BM * BK / 256;
    constexpr int W_ELEMS = BK * BN / 256;

    for (int kc = 0; kc < K; kc += BK) {
        // stage A tile (transposed to k-major)
        #pragma unroll
        for (int i = 0; i < A_ELEMS; ++i) {
            int e = i * 256 + tid;
            int m = e >> 5;        // e / BK
            int j = e & 31;        // e % BK
            int gm = mblk + m;
            int gk = kc + j;
            float v;
            if constexpr (MODE == 0) {
                v = Aptr[(size_t)gm * K + gk];
            } else {
                if (gk < EE)            v = emb[(size_t)y[gm * (TT + 1) + t] * EE + gk];
                else if (gk < EE + FF)  v = ctx[(size_t)gm * FF + (gk - EE)];
                else                    v = hptr[(size_t)gm * HH + (gk - EE - FF)];
            }
            lds_a[j][m] = v;
        }
        // stage W tile
        #pragma unroll
        for (int i = 0; i < W_ELEMS; ++i) {
            int e = i * 256 + tid;
            int j = e / BN;
            int n = e % BN;
            int gk = kc + j;
            const float* wrow;
            if constexpr (MODE == 2)
                wrow = (gk < EE + FF) ? (W + (size_t)gk * N) : (W2 + (size_t)(gk - (EE + FF)) * N);
            else
                wrow = W + (size_t)gk * N;
            lds_w[j][n] = wrow[nblk + n];
        }
        __syncthreads();
        #pragma unroll
        for (int k = 0; k < BK; ++k) {
            float av[TM], wv[TN];
            #pragma unroll
            for (int i = 0; i < TM; ++i) av[i] = lds_a[k][tm + i];
            #pragma unroll
            for (int j = 0; j < TN; ++j) wv[j] = lds_w[k][tn + j];
            #pragma unroll
            for (int i = 0; i < TM; ++i)
                #pragma unroll
                for (int j = 0; j < TN; ++j)
                    acc[i][j] = fmaf(av[i], wv[j], acc[i][j]);
        }
        __syncthreads();
    }
    // epilogue
    #pragma unroll
    for (int i = 0; i < TM; ++i) {
        int gm = mblk + tm + i;
        #pragma unroll
        for (int j = 0; j < TN; ++j) {
            int gn = nblk + tn + j;
            float v = acc[i][j] + bias[gn];
            if constexpr (MODE == 2) v += bias2[gn];
            C[(size_t)gm * Cstride + gn] = v;
        }
    }
}

// ---------------------------------------------------------------------------
// Attention: scores -> softmax -> alpha (one block per batch row)
__global__ __launch_bounds__(256)
void attn_kernel(const float* __restrict__ x_enc, const float* __restrict__ xd,
                 const float* __restrict__ score_w, const float* __restrict__ score_b,
                 float* __restrict__ alpha_ws, float* __restrict__ out_alpha, int t)
{
    __shared__ float lds_xd[AA];
    __shared__ float lds_sw[AA];
    __shared__ float part[LL][4];
    int b = blockIdx.x, tid = threadIdx.x;
    for (int j = tid; j < AA; j += 256) {
        lds_xd[j] = xd[b * AA + j];
        lds_sw[j] = score_w[j];
    }
    __syncthreads();
    int l = tid >> 2, q = tid & 3;               // 64 rows x 4 partials
    const float* xr = x_enc + ((size_t)(b * LL) + l) * AA + q * 128;
    float s = 0.f;
    #pragma unroll 4
    for (int j = 0; j < 128; ++j)
        s += tanhf(xr[j] + lds_xd[q * 128 + j]) * lds_sw[q * 128 + j];
    part[l][q] = s;
    __syncthreads();
    if (tid < 64) {   // lanes 0..63 = wave 0
        float sc = part[tid][0] + part[tid][1] + part[tid][2] + part[tid][3] + score_b[0];
        float m = sc;
        for (int off = 32; off; off >>= 1) m = fmaxf(m, __shfl_xor(m, off));
        float e = expf(sc - m);
        float sum = e;
        for (int off = 32; off; off >>= 1) sum += __shfl_xor(sum, off);
        float al = e / sum;
        alpha_ws[b * LL + tid] = al;
        out_alpha[((size_t)b * TT + t) * LL + tid] = al;
    }
}

// ---------------------------------------------------------------------------
// context[b,f] = sum_l X[b,l,f] * alpha[b,l]
__global__ __launch_bounds__(256)
void context_kernel(const float* __restrict__ X, const float* __restrict__ alpha,
                    float* __restrict__ context)
{
    int idx = blockIdx.x * 256 + threadIdx.x;  // over B*F
    int b = idx >> 11, f = idx & (FF - 1);
    const float* xp = X + (size_t)b * LL * FF + f;
    const float* al = alpha + b * LL;
    float s = 0.f;
    #pragma unroll
    for (int l = 0; l < LL; ++l) s = fmaf(xp[l * FF], al[l], s);
    context[idx] = s;
}

// ---------------------------------------------------------------------------
// LSTM pointwise: gates [B,4H] (i,f,g,o) -> update h,c in place
__global__ __launch_bounds__(256)
void lstm_kernel(const float* __restrict__ gates, float* __restrict__ h, float* __restrict__ c)
{
    int idx = blockIdx.x * 256 + threadIdx.x;  // over B*H
    int b = idx >> 10, n = idx & (HH - 1);
    const float* g = gates + (size_t)b * 4 * HH;
    float gi = g[n], gf = g[HH + n], gg = g[2 * HH + n], go = g[3 * HH + n];
    float si = 1.f / (1.f + expf(-gi));
    float sf = 1.f / (1.f + expf(-gf));
    float so = 1.f / (1.f + expf(-go));
    float c2 = sf * c[idx] + si * tanhf(gg);
    float h2 = so * tanhf(c2);
    c[idx] = c2;
    h[idx] = h2;
}

// ---------------------------------------------------------------------------
extern "C" void kernel_launch(void* const* d_in, const int* in_sizes, int n_in,
                              void* d_out, int out_size, void* d_ws, size_t ws_size,
                              hipStream_t stream) {
    const float* X       = (const float*)d_in[0];
    const int*   y       = (const int*)d_in[1];
    const float* emb     = (const float*)d_in[2];
    const float* fc1_w   = (const float*)d_in[3];
    const float* fc1_b   = (const float*)d_in[4];
    const float* fc2_w   = (const float*)d_in[5];
    const float* fc2_b   = (const float*)d_in[6];
    const float* score_w = (const float*)d_in[7];
    const float* score_b = (const float*)d_in[8];
    const float* sm_w    = (const float*)d_in[9];
    const float* sm_b    = (const float*)d_in[10];
    const float* lm_w    = (const float*)d_in[11];
    const float* lm_b    = (const float*)d_in[12];
    const float* w_ih    = (const float*)d_in[13];
    const float* b_ih    = (const float*)d_in[14];
    const float* w_hh    = (const float*)d_in[15];
    const float* b_hh    = (const float*)d_in[16];
    const float* out_w   = (const float*)d_in[17];
    const float* out_b   = (const float*)d_in[18];

    float* out = (float*)d_out;
    float* out_alpha = out + (size_t)BB * TT * VV;   // outputs then weights, flat

    float* ws = (float*)d_ws;
    float* mean_ann = ws;  ws += (size_t)BB * FF;
    float* hbuf     = ws;  ws += (size_t)BB * HH;
    float* cbuf     = ws;  ws += (size_t)BB * HH;
    float* x_enc    = ws;  ws += (size_t)BB * LL * AA;
    float* xd       = ws;  ws += (size_t)BB * AA;
    float* alpha    = ws;  ws += (size_t)BB * LL;
    float* context  = ws;  ws += (size_t)BB * FF;
    float* gates    = ws;  ws += (size_t)BB * 4 * HH;

    // --- precompute ---
    mean_kernel<<<BB * FF / 256, 256, 0, stream>>>(X, mean_ann);
    // h0 = mean_ann @ sm_w + sm_b   [128,2048]x[2048,1024]
    tgemm<64, 32, 4, 2, 0><<<dim3(HH / 32, BB / 64), 256, 0, stream>>>(
        mean_ann, nullptr, nullptr, nullptr, nullptr, 0,
        sm_w, nullptr, sm_b, nullptr, hbuf, HH, FF, HH);
    // c0 = mean_ann @ lm_w + lm_b
    tgemm<64, 32, 4, 2, 0><<<dim3(HH / 32, BB / 64), 256, 0, stream>>>(
        mean_ann, nullptr, nullptr, nullptr, nullptr, 0,
        lm_w, nullptr, lm_b, nullptr, cbuf, HH, FF, HH);
    // x_enc = X @ fc2_w + fc2_b   [8192,2048]x[2048,512]
    tgemm<128, 64, 8, 4, 0><<<dim3(AA / 64, (BB * LL) / 128), 256, 0, stream>>>(
        X, nullptr, nullptr, nullptr, nullptr, 0,
        fc2_w, nullptr, fc2_b, nullptr, x_enc, AA, FF, AA);

    // --- decode loop ---
    for (int t = 0; t < TT; ++t) {
        // xd = h @ fc1_w + fc1_b   [128,1024]x[1024,512]
        tgemm<64, 32, 4, 2, 0><<<dim3(AA / 32, BB / 64), 256, 0, stream>>>(
            hbuf, nullptr, nullptr, nullptr, nullptr, 0,
            fc1_w, nullptr, fc1_b, nullptr, xd, AA, HH, AA);
        // attention softmax + alpha output
        attn_kernel<<<BB, 256, 0, stream>>>(x_enc, xd, score_w, score_b, alpha, out_alpha, t);
        // context = alpha @ X
        context_kernel<<<BB * FF / 256, 256, 0, stream>>>(X, alpha, context);
        // gates = [emb_t | context] @ w_ih + h @ w_hh + b_ih + b_hh   K=3584, N=4096
        tgemm<64, 32, 4, 2, 2><<<dim3(4 * HH / 32, BB / 64), 256, 0, stream>>>(
            nullptr, context, hbuf, emb, y, t,
            w_ih, w_hh, b_ih, b_hh, gates, 4 * HH, EE + FF + HH, 4 * HH);
        // LSTM pointwise -> h,c updated in place
        lstm_kernel<<<BB * HH / 256, 256, 0, stream>>>(gates, hbuf, cbuf);
        // logits = h2 @ out_w + out_b -> out[(b*T+t)*V + v]   [128,1024]x[1024,32000]
        tgemm<128, 64, 8, 4, 0><<<dim3(VV / 64, BB / 128), 256, 0, stream>>>(
            hbuf, nullptr, nullptr, nullptr, nullptr, 0,
            out_w, nullptr, out_b, nullptr, out + (size_t)t * VV, VV, HH, TT * VV);
    }
}